// Round 2
// baseline (299.029 us; speedup 1.0000x reference)
//
#include <hip/hip_runtime.h>

// Problem constants (B=8, L=2048, H=256). All float tensors are fp32.
#define B_ 8
#define L_ 2048
#define H_ 256

typedef _Float16 half8 __attribute__((ext_vector_type(8)));
typedef _Float16 half2_t __attribute__((ext_vector_type(2)));
typedef float f32x4 __attribute__((ext_vector_type(4)));

// ---------------------------------------------------------------------------
// Kernel 1: prep — st[b,i] = tanh(text@Wt^T + bt) @ wa[:H]
//                  c[b,j]  = tanh(opin@Wo^T) @ wa[H:] + ba
//                  mult[b,j] = 8 if pos_ids in opinion list else 1
// 16 rows per block (amortizes Wt/Wo L2 refetch), 256 threads (thread = h).
// ---------------------------------------------------------------------------
__global__ __launch_bounds__(256) void prep_kernel(
    const float* __restrict__ opin,
    const float* __restrict__ text,
    const int* __restrict__ pos_ids,
    const float* __restrict__ Wt,
    const float* __restrict__ bt,
    const float* __restrict__ Wo,
    const float* __restrict__ wa,
    const float* __restrict__ ba,
    float* __restrict__ ws_st, float* __restrict__ ws_c,
    float* __restrict__ ws_mult)
{
    __shared__ __align__(16) float lt[16][256];
    __shared__ __align__(16) float lo[16][256];
    __shared__ float redT[4][16];
    __shared__ float redO[4][16];
    const int tid = threadIdx.x;
    const int wid = tid >> 6, lane = tid & 63;
    const size_t g0 = (size_t)blockIdx.x * 16;

    for (int r = 0; r < 16; ++r) {
        lt[r][tid] = text[(g0 + r) * 256 + tid];
        lo[r][tid] = opin[(g0 + r) * 256 + tid];
    }
    __syncthreads();

    const int h = tid;
    float accT[16], accO[16];
    const float btv = bt[h];
#pragma unroll
    for (int r = 0; r < 16; ++r) { accT[r] = btv; accO[r] = 0.f; }

    const float4* wtr = (const float4*)(Wt + h * 256);
    const float4* wor = (const float4*)(Wo + h * 256);
    for (int k4 = 0; k4 < 64; ++k4) {
        const float4 wt4 = wtr[k4];
        const float4 wo4 = wor[k4];
#pragma unroll
        for (int r = 0; r < 16; ++r) {
            const float4 tv = *(const float4*)&lt[r][k4 * 4];  // LDS broadcast
            const float4 ov = *(const float4*)&lo[r][k4 * 4];
            accT[r] = fmaf(wt4.x, tv.x, fmaf(wt4.y, tv.y, fmaf(wt4.z, tv.z, fmaf(wt4.w, tv.w, accT[r]))));
            accO[r] = fmaf(wo4.x, ov.x, fmaf(wo4.y, ov.y, fmaf(wo4.z, ov.z, fmaf(wo4.w, ov.w, accO[r]))));
        }
    }

    const float wah = wa[h], wbh = wa[256 + h];
    for (int r = 0; r < 16; ++r) {
        float vt = tanhf(accT[r]) * wah;
        float vo = tanhf(accO[r]) * wbh;
#pragma unroll
        for (int off = 32; off; off >>= 1) {
            vt += __shfl_xor(vt, off, 64);
            vo += __shfl_xor(vo, off, 64);
        }
        if (lane == 0) { redT[wid][r] = vt; redO[wid][r] = vo; }
    }
    __syncthreads();

    if (tid < 16) {
        ws_st[g0 + tid] = redT[0][tid] + redT[1][tid] + redT[2][tid] + redT[3][tid];
    } else if (tid < 32) {
        const int r = tid - 16;
        ws_c[g0 + r] = redO[0][r] + redO[1][r] + redO[2][r] + redO[3][r] + ba[0];
    } else if (tid < 48) {
        const int r = tid - 32;
        const int p = pos_ids[g0 + r];
        const bool isop = (p == 19) | (p == 20) | (p == 21) | (p == 33) | (p == 34) |
                          (p == 35) | ((p >= 41) & (p <= 46));
        ws_mult[g0 + r] = isop ? 8.0f : 1.0f;
    }
}

// ---------------------------------------------------------------------------
// Kernel 2: attention. Block = (batch b, 32-row i-tile), 256 thr = 4 waves:
// wave (rg = wid&1 -> 16-row group, hh = wid>>1 -> 128-col h half).
// s_ij = (st_i + c_j) * (mult_j * base(|i-j|)); exact row-max prepass;
// K-chunks of 64: stage V^T (fp16, XOR-swizzled) + P tile (fp16) in LDS,
// MFMA f32_16x16x32_f16; normalize by Z in epilogue.
// ---------------------------------------------------------------------------
#define TI 32
#define KC 64

__global__ __launch_bounds__(256, 2) void attn_kernel(
    const float* __restrict__ opin,
    const float* __restrict__ ws_st,
    const float* __restrict__ ws_c,
    const float* __restrict__ ws_mult,
    float* __restrict__ out)
{
    __shared__ float base_tbl[2048];
    __shared__ float c_arr[2048];
    __shared__ float m_arr[2048];
    __shared__ float st_tile[TI];
    __shared__ float m_i[TI];
    __shared__ float zpart[2][TI];
    __shared__ __align__(16) _Float16 p_lds[2][16][KC];       // P tiles per row-group
    __shared__ __align__(16) _Float16 vt_lds[256 * KC];       // V^T, XOR-swizzled k-blocks

    const int tid = threadIdx.x;
    const int wid = tid >> 6, lane = tid & 63;
    const int rg = wid & 1, hh = wid >> 1;
    const int b = blockIdx.x & 7;          // batch -> XCD locality heuristic
    const int i0 = (blockIdx.x >> 3) * TI;

    for (int j = tid; j < 2048; j += 256) {
        c_arr[j] = ws_c[b * 2048 + j];
        m_arr[j] = ws_mult[b * 2048 + j];
        base_tbl[j] = (j == 0) ? 0.5f : 1.0f / log2f(2.0f + (float)j);
    }
    if (tid < TI) st_tile[tid] = ws_st[b * 2048 + i0 + tid];
    __syncthreads();

    // Pass 1: exact row max (wave wid handles rows wid*8 .. wid*8+7)
    for (int rr = 0; rr < 8; ++rr) {
        const int row = wid * 8 + rr;
        const int i = i0 + row;
        const float sti_r = st_tile[row];
        float mx = -3.4e38f;
        for (int j = lane; j < 2048; j += 64) {
            const int d = (i > j) ? (i - j) : (j - i);
            const float s = (sti_r + c_arr[j]) * (m_arr[j] * base_tbl[d]);
            mx = fmaxf(mx, s);
        }
#pragma unroll
        for (int off = 32; off; off >>= 1) mx = fmaxf(mx, __shfl_xor(mx, off, 64));
        if (lane == 0) m_i[row] = mx;
    }
    __syncthreads();

    // Main K loop
    f32x4 acc[8];
    const f32x4 zero4 = {0.f, 0.f, 0.f, 0.f};
#pragma unroll
    for (int t = 0; t < 8; ++t) acc[t] = zero4;

    float zacc = 0.f;
    const int prow = lane >> 2;            // P row this lane computes (0..15)
    const int grow = rg * 16 + prow;
    const float sti = st_tile[grow];
    const float mi = m_i[grow];
    const int gi = i0 + grow;
    const int jseg = (lane & 3) * 8;       // 8-wide j segment within 32-wide half

    for (int kc = 0; kc < 32; ++kc) {
        const int j0 = kc * KC;
        // --- stage V^T tile (thread = h column) ---
        {
            const int hcol = tid;
            const float* vp = opin + ((size_t)b * 2048 + j0) * 256 + hcol;
            const int hsw = (hcol & 7) << 3;
#pragma unroll
            for (int jj = 0; jj < KC; jj += 2) {
                const float v0 = vp[jj * 256];
                const float v1 = vp[(jj + 1) * 256];
                half2_t pr = {(_Float16)v0, (_Float16)v1};
                const int off = hcol * 64 + ((((jj >> 3) << 3)) ^ hsw) + (jj & 7);
                *(half2_t*)&vt_lds[off] = pr;
            }
        }
        // --- compute P tile: wave (rg,hh) covers rows rg*16..+15, j hh*32..+31 ---
        {
            const int jb = j0 + hh * 32 + jseg;
            half8 pv;
            float zl = 0.f;
#pragma unroll
            for (int v = 0; v < 8; ++v) {
                const int j = jb + v;
                const int d = (gi > j) ? (gi - j) : (j - gi);
                const float s = (sti + c_arr[j]) * (m_arr[j] * base_tbl[d]);
                const float p = __expf(s - mi);
                zl += p;
                pv[v] = (_Float16)p;
            }
            zacc += zl;
            *(half8*)&p_lds[rg][prow][hh * 32 + jseg] = pv;
        }
        __syncthreads();
        // --- MFMA: 2 k-subchunks x 8 h-tiles ---
        {
            const int m = lane & 15;
            const int q = lane >> 4;
            const half8 a0 = *(const half8*)&p_lds[rg][m][q * 8];
            const half8 a1 = *(const half8*)&p_lds[rg][m][32 + q * 8];
#pragma unroll
            for (int ht = 0; ht < 8; ++ht) {
                const int hcol = hh * 128 + ht * 16 + m;
                const int hsw = (hcol & 7) << 3;
                const half8 b0 = *(const half8*)&vt_lds[hcol * 64 + ((q << 3) ^ hsw)];
                const half8 b1 = *(const half8*)&vt_lds[hcol * 64 + (((q + 4) << 3) ^ hsw)];
                acc[ht] = __builtin_amdgcn_mfma_f32_16x16x32_f16(a0, b0, acc[ht], 0, 0, 0);
                acc[ht] = __builtin_amdgcn_mfma_f32_16x16x32_f16(a1, b1, acc[ht], 0, 0, 0);
            }
        }
        __syncthreads();
    }

    // Z reduction: lanes 4r..4r+3 hold partials for the same row
    zacc += __shfl_xor(zacc, 1, 64);
    zacc += __shfl_xor(zacc, 2, 64);
    if ((lane & 3) == 0) zpart[hh][grow] = zacc;
    __syncthreads();

    // Epilogue: C/D layout col = lane&15, row = (lane>>4)*4 + reg
    {
        const int m = lane & 15;
        const int q = lane >> 4;
        float rz[4];
#pragma unroll
        for (int r = 0; r < 4; ++r) {
            const int orow = rg * 16 + q * 4 + r;
            rz[r] = 1.0f / (zpart[0][orow] + zpart[1][orow]);
        }
#pragma unroll
        for (int ht = 0; ht < 8; ++ht) {
            const int hcol = hh * 128 + ht * 16 + m;
#pragma unroll
            for (int r = 0; r < 4; ++r) {
                const int orow = rg * 16 + q * 4 + r;
                out[((size_t)b * 2048 + (i0 + orow)) * 256 + hcol] = acc[ht][r] * rz[r];
            }
        }
    }
}

// ---------------------------------------------------------------------------
extern "C" void kernel_launch(void* const* d_in, const int* in_sizes, int n_in,
                              void* d_out, int out_size, void* d_ws, size_t ws_size,
                              hipStream_t stream) {
    const float* opin  = (const float*)d_in[0];
    const float* text  = (const float*)d_in[1];
    const int* pos_ids = (const int*)d_in[2];
    const float* Wt    = (const float*)d_in[3];
    const float* bt    = (const float*)d_in[4];
    const float* Wo    = (const float*)d_in[5];
    const float* wa    = (const float*)d_in[6];
    const float* ba    = (const float*)d_in[7];
    float* out         = (float*)d_out;

    float* ws      = (float*)d_ws;
    float* ws_st   = ws;                 // B*L
    float* ws_c    = ws + B_ * L_;       // B*L
    float* ws_mult = ws + 2 * B_ * L_;   // B*L

    prep_kernel<<<B_ * L_ / 16, 256, 0, stream>>>(opin, text, pos_ids, Wt, bt, Wo,
                                                  wa, ba, ws_st, ws_c, ws_mult);
    attn_kernel<<<B_ * (L_ / TI), 256, 0, stream>>>(opin, ws_st, ws_c, ws_mult, out);
}

// Round 3
// 175.813 us; speedup vs baseline: 1.7008x; 1.7008x over previous
//
#include <hip/hip_runtime.h>

// Problem: B=8, L=2048, H=256. fp32 in/out.
#define B_ 8
#define L_ 2048
#define H_ 256

typedef _Float16 half8 __attribute__((ext_vector_type(8)));
typedef _Float16 half4_t __attribute__((ext_vector_type(4)));
typedef float f32x4 __attribute__((ext_vector_type(4)));

__device__ __forceinline__ float fast_tanh(float x) {
    const float e2 = __expf(2.f * x);
    return 1.f - 2.f * __builtin_amdgcn_rcpf(e2 + 1.f);
}

// ---------------------------------------------------------------------------
// prep: one block = 64 rows of text (mat=0) or opin (mat=1).
// MFMA GEMM rows@W^T (fp16 in, fp32 acc), epilogue tanh/wa reduce.
// mat=0 -> ws_st[row]; mat=1 -> ws_cm[row]={c*mult,mult} and V^T fp16 -> vtg.
// LDS frag-linear layouts: frag reads are lane*16B (bank-balanced b128).
// ---------------------------------------------------------------------------
__global__ __launch_bounds__(256, 2) void prep_kernel(
    const float* __restrict__ opin, const float* __restrict__ text,
    const int* __restrict__ pos_ids,
    const float* __restrict__ Wt, const float* __restrict__ bt,
    const float* __restrict__ Wo, const float* __restrict__ wa,
    const float* __restrict__ ba,
    float* __restrict__ ws_st, float2* __restrict__ ws_cm,
    _Float16* __restrict__ vtg)
{
    __shared__ __align__(16) _Float16 a_lds[4][8][512];  // [rowgrp][kchunk][frag-linear]
    __shared__ __align__(16) _Float16 w_lds[16][512];    // [ntile][frag-linear], per chunk

    const int tid  = threadIdx.x;
    const int lane = tid & 63;
    const int rg   = tid >> 6;                 // wave id = 16-row group
    const int mat  = blockIdx.x & 1;           // 0=text, 1=opin
    const size_t g0 = (size_t)(blockIdx.x >> 1) * 64;   // first flattened row (b*L+i)

    const float* __restrict__ src = mat ? opin : text;
    const float* __restrict__ W   = mat ? Wo   : Wt;

    // ---- stage A: 64 rows x 256 k, fp32 -> fp16, frag-linear per (rg, kc) ----
    for (int v = 0; v < 16; ++v) {
        const int idx = v * 256 + tid;      // float4 index in 64x64 grid
        const int row = idx >> 6;           // 0..63
        const int k   = (idx & 63) * 4;     // 0..252
        const float4 f = *(const float4*)(src + (g0 + row) * 256 + k);
        half4_t h = { (_Float16)f.x, (_Float16)f.y, (_Float16)f.z, (_Float16)f.w };
        const int off = ((row & 15) + 16 * ((k >> 3) & 3)) * 8 + (k & 7); // k&7 in {0,4}
        *(half4_t*)&a_lds[row >> 4][k >> 5][off] = h;
    }
    __syncthreads();

    f32x4 acc[16];
#pragma unroll
    for (int nt = 0; nt < 16; ++nt) acc[nt] = (f32x4){0.f, 0.f, 0.f, 0.f};

    for (int kc = 0; kc < 8; ++kc) {
        // stage W chunk: 256 n x 32 k
        for (int p = 0; p < 8; ++p) {
            const int n = p * 32 + (tid >> 3);
            const int k = (tid & 7) * 4;    // within chunk
            const float4 f = *(const float4*)(W + n * 256 + kc * 32 + k);
            half4_t h = { (_Float16)f.x, (_Float16)f.y, (_Float16)f.z, (_Float16)f.w };
            const int off = ((n & 15) + 16 * (k >> 3)) * 8 + (k & 7);
            *(half4_t*)&w_lds[n >> 4][off] = h;
        }
        __syncthreads();
        const half8 afrag = *(const half8*)&a_lds[rg][kc][lane * 8];
#pragma unroll
        for (int nt = 0; nt < 16; ++nt) {
            const half8 bfrag = *(const half8*)&w_lds[nt][lane * 8];
            acc[nt] = __builtin_amdgcn_mfma_f32_16x16x32_f16(afrag, bfrag, acc[nt], 0, 0, 0);
        }
        __syncthreads();
    }

    // ---- epilogue: rowsum_n( tanh(acc + bt?) * wa ) ----
    const int em = lane & 15, q = lane >> 4;
    float rowsum[4] = {0.f, 0.f, 0.f, 0.f};
#pragma unroll
    for (int nt = 0; nt < 16; ++nt) {
        const int col  = nt * 16 + em;
        const float btv = mat ? 0.f : bt[col];
        const float wav = wa[mat * 256 + col];
#pragma unroll
        for (int r = 0; r < 4; ++r)
            rowsum[r] += fast_tanh(acc[nt][r] + btv) * wav;
    }
#pragma unroll
    for (int r = 0; r < 4; ++r) {
        float s = rowsum[r];
        s += __shfl_xor(s, 1, 64);
        s += __shfl_xor(s, 2, 64);
        s += __shfl_xor(s, 4, 64);
        s += __shfl_xor(s, 8, 64);
        if (em == 0) {
            const size_t grow = g0 + rg * 16 + q * 4 + r;
            if (mat == 0) {
                ws_st[grow] = s;
            } else {
                const int p = pos_ids[grow];
                const bool isop = (p==19)|(p==20)|(p==21)|(p==33)|(p==34)|(p==35)|((p>=41)&(p<=46));
                const float mult = isop ? 8.f : 1.f;
                const float c = s + ba[0];
                ws_cm[grow] = make_float2(c * mult, mult);
            }
        }
    }

    // ---- V^T emission (opin blocks): vtg[(b*256+h)*2048 + j] fp16 ----
    if (mat == 1) {
        const int h = tid;
        const size_t b = g0 >> 11;
        const int j0 = (int)(g0 & 2047);
        const int kc = h >> 5, kq = (h >> 3) & 3, jh = h & 7;
        _Float16 vals[64];
#pragma unroll
        for (int r = 0; r < 64; ++r)
            vals[r] = a_lds[r >> 4][kc][((r & 15) + 16 * kq) * 8 + jh];
        _Float16* dst = vtg + ((b * 256 + h) * 2048 + j0);
#pragma unroll
        for (int w = 0; w < 8; ++w)
            *(half8*)(dst + w * 8) = *(half8*)&vals[w * 8];
    }
}

// ---------------------------------------------------------------------------
// attn: block = (batch b, 64-row i-tile, 128-col h-half). 4 waves (rgp, hq):
// rgp -> 32 rows, hq -> 64 h-cols (MFMA) and 32-j half (P scores).
// Online softmax (no prepass). V^T staged fp16 b128 from vtg (XOR-swizzled).
// base bias computed in VALU: d==0 ? 0.5 : rcp(log2(2+d)).
// ---------------------------------------------------------------------------
__global__ __launch_bounds__(256, 2) void attn_kernel(
    const float* __restrict__ ws_st, const float2* __restrict__ ws_cm,
    const _Float16* __restrict__ vtg, float* __restrict__ out)
{
    __shared__ __align__(16) _Float16 vt_lds[128 * 64];   // [h 128][j 64 swizzled]
    __shared__ __align__(16) _Float16 p_lds[4][2][512];   // [rowtile][jhalf][frag-linear]
    __shared__ float mloc[2][64];
    __shared__ float zpart[2][64];

    const int tid  = threadIdx.x;
    const int lane = tid & 63;
    const int wid  = tid >> 6;
    const int rgp  = wid & 1;                 // rows rgp*32 .. +31
    const int hq   = wid >> 1;                // h quarter / j half
    const int b     = blockIdx.x & 7;
    const int i0    = ((blockIdx.x >> 3) & 31) * 64;
    const int hhalf = blockIdx.x >> 8;
    const int h0    = hhalf * 128;

    const int r64 = rgp * 32 + (lane >> 1);   // this lane's P row (0..63)
    const int gi  = i0 + r64;
    const float sti = ws_st[b * 2048 + gi];
    const int jbase_lane = hq * 32 + (lane & 1) * 16;  // lane's 16-j segment within chunk

    f32x4 acc[2][4];
#pragma unroll
    for (int rt = 0; rt < 2; ++rt)
#pragma unroll
        for (int ht = 0; ht < 4; ++ht) acc[rt][ht] = (f32x4){0.f, 0.f, 0.f, 0.f};
    float zacc = 0.f;
    float m_run = -1e30f;

    for (int kc = 0; kc < 32; ++kc) {
        const int j0 = kc * 64;
        // --- phase 1a: stage V^T tile (128 h x 64 j) fp16, swizzled b128 copy ---
#pragma unroll
        for (int it = 0; it < 4; ++it) {
            const int h   = it * 32 + (tid >> 3);
            const int jb8 = tid & 7;
            const half8 v = *(const half8*)(vtg + ((size_t)(b * 256 + h0 + h) * 2048 + j0 + jb8 * 8));
            *(half8*)&vt_lds[h * 64 + ((jb8 ^ (h & 7)) * 8)] = v;
        }
        // --- phase 1b: scores for (row r64) x 16 j ---
        float s_arr[16];
        float mx = -1e30f;
        {
            const float4* cmp = (const float4*)(ws_cm + b * 2048 + j0 + jbase_lane);
#pragma unroll
            for (int w8 = 0; w8 < 8; ++w8) {
                const float4 c4 = cmp[w8];   // {c*m, m} x2
                const int j = j0 + jbase_lane + w8 * 2;
                int d0 = gi - j;     d0 = d0 < 0 ? -d0 : d0;
                int d1 = gi - j - 1; d1 = d1 < 0 ? -d1 : d1;
                float b0 = __builtin_amdgcn_rcpf(__log2f(2.f + (float)d0));
                float b1 = __builtin_amdgcn_rcpf(__log2f(2.f + (float)d1));
                b0 = (d0 == 0) ? 0.5f : b0;
                b1 = (d1 == 0) ? 0.5f : b1;
                const float s0 = (sti * c4.y + c4.x) * b0;
                const float s1 = (sti * c4.w + c4.z) * b1;
                s_arr[w8 * 2]     = s0;
                s_arr[w8 * 2 + 1] = s1;
                mx = fmaxf(mx, fmaxf(s0, s1));
            }
        }
        mx = fmaxf(mx, __shfl_xor(mx, 1, 64));   // combine the row's 2 owner lanes
        if ((lane & 1) == 0) mloc[hq][r64] = mx;
        __syncthreads();   // barrier 1: vt_lds staged + mloc visible

        // --- phase 2: online-softmax update, exp, write P frag-linear ---
        const float m_new = fmaxf(m_run, fmaxf(mloc[0][r64], mloc[1][r64]));
        if (__any(m_new > m_run)) {
            const float alpha = __expf(m_run - m_new);   // 1.0 for non-updated rows
            const int q = lane >> 4;
#pragma unroll
            for (int rt = 0; rt < 2; ++rt)
#pragma unroll
                for (int reg = 0; reg < 4; ++reg) {
                    const float av = __shfl(alpha, (rt * 16 + q * 4 + reg) * 2, 64);
#pragma unroll
                    for (int ht = 0; ht < 4; ++ht) acc[rt][ht][reg] *= av;
                }
            zacc *= alpha;
            m_run = m_new;
        }
        {
            half8 pv0, pv1;
            float zl = 0.f;
#pragma unroll
            for (int v = 0; v < 8; ++v) {
                const float p = __expf(s_arr[v] - m_run);
                zl += p; pv0[v] = (_Float16)p;
            }
#pragma unroll
            for (int v = 0; v < 8; ++v) {
                const float p = __expf(s_arr[8 + v] - m_run);
                zl += p; pv1[v] = (_Float16)p;
            }
            zacc += zl;
            const int rti = r64 >> 4, mrow = r64 & 15, kq0 = (lane & 1) * 2;
            *(half8*)&p_lds[rti][hq][(mrow + 16 * kq0) * 8]       = pv0;
            *(half8*)&p_lds[rti][hq][(mrow + 16 * (kq0 + 1)) * 8] = pv1;
        }
        __syncthreads();   // barrier 2: p_lds complete

        // --- phase 3: MFMA ---
        {
            const int em = lane & 15, q = lane >> 4;
#pragma unroll
            for (int s = 0; s < 2; ++s) {
                const half8 a0 = *(const half8*)&p_lds[rgp * 2 + 0][s][lane * 8];
                const half8 a1 = *(const half8*)&p_lds[rgp * 2 + 1][s][lane * 8];
#pragma unroll
                for (int ht = 0; ht < 4; ++ht) {
                    const int hcol = hq * 64 + ht * 16 + em;
                    const int jblk = s * 4 + q;
                    const half8 bf = *(const half8*)&vt_lds[hcol * 64 + ((jblk ^ (hcol & 7)) * 8)];
                    acc[0][ht] = __builtin_amdgcn_mfma_f32_16x16x32_f16(a0, bf, acc[0][ht], 0, 0, 0);
                    acc[1][ht] = __builtin_amdgcn_mfma_f32_16x16x32_f16(a1, bf, acc[1][ht], 0, 0, 0);
                }
            }
        }
        __syncthreads();   // barrier 3: protect vt_lds/p_lds for next chunk
    }

    // --- Z finalize: sum the row's 2 owner lanes, then across hq waves ---
    zacc += __shfl_xor(zacc, 1, 64);
    if ((lane & 1) == 0) zpart[hq][r64] = zacc;
    __syncthreads();

    // --- epilogue: normalize, store. C/D: col=lane&15, row=(lane>>4)*4+reg ---
    {
        const int em = lane & 15, q = lane >> 4;
#pragma unroll
        for (int rt = 0; rt < 2; ++rt) {
#pragma unroll
            for (int reg = 0; reg < 4; ++reg) {
                const int row = rgp * 32 + rt * 16 + q * 4 + reg;
                const float rz = 1.f / (zpart[0][row] + zpart[1][row]);
#pragma unroll
                for (int ht = 0; ht < 4; ++ht) {
                    const int col = h0 + hq * 64 + ht * 16 + em;
                    out[((size_t)b * 2048 + (i0 + row)) * 256 + col] = acc[rt][ht][reg] * rz;
                }
            }
        }
    }
}

// ---------------------------------------------------------------------------
extern "C" void kernel_launch(void* const* d_in, const int* in_sizes, int n_in,
                              void* d_out, int out_size, void* d_ws, size_t ws_size,
                              hipStream_t stream) {
    const float* opin  = (const float*)d_in[0];
    const float* text  = (const float*)d_in[1];
    const int* pos_ids = (const int*)d_in[2];
    const float* Wt    = (const float*)d_in[3];
    const float* bt    = (const float*)d_in[4];
    const float* Wo    = (const float*)d_in[5];
    const float* wa    = (const float*)d_in[6];
    const float* ba    = (const float*)d_in[7];
    float* out         = (float*)d_out;

    // workspace: st (64 KB) | cm (128 KB) | vtg fp16 (8 MB)
    float*  ws_st = (float*)d_ws;
    float2* ws_cm = (float2*)((char*)d_ws + 65536);
    _Float16* vtg = (_Float16*)((char*)d_ws + 65536 + 131072);

    prep_kernel<<<512, 256, 0, stream>>>(opin, text, pos_ids, Wt, bt, Wo, wa, ba,
                                         ws_st, ws_cm, vtg);
    attn_kernel<<<512, 256, 0, stream>>>(ws_st, ws_cm, vtg, out);
}